// Round 6
// baseline (13120.306 us; speedup 1.0000x reference)
//
#include <hip/hip_runtime.h>
#include <hip/hip_bf16.h>
#include <hip/hip_fp16.h>

// Hypernetwork RNN scan. B=16, N=2048, M=H=64, L*E=1024, Cout=256.
// Round 19: single-WG-per-batch, fitted to the register caps.
// R14/R15/R16 all violated the 256 architected-VGPR/lane cap (296/416/
// SSA-AGPR demand) and spilled to scratch. R17/R18 showed cross-WG
// exchange cannot go faster than the LLC RTT (XCD-local mailboxes never
// turn over: consumer L2 lines stay stale for plain stores).
// This round: 512 threads/WG, per-thread Wd slice = 8 h-rows:
//   6 rows -> arch VGPRs (wreg[48] = 192 regs; total demand ~232 < 256)
//   2 rows -> resident LDS (128 KB, read per step, overlaps VALU)
// Wdb/bdec slices live in per-thread regs (4+4 u32); their dot products
// are spread across all 8 waves (4 dot2 each) + LDS partial reduce.
// Per step: 256 dot2/thread (1024 cyc VALU) + 128 KB LDS + 3 barriers,
// ZERO cross-WG traffic. Sum trees: 8-way partials (R15 empirically
// showed tree restructure keeps absmax at 0.0625).
//   K1 cvt: Wd->f16 per-thread layout; enc m-rows->f16; dec_w->bf16
//   K2 build_T (f32, 8 MB), K3 build_P (f32, 16 MB)
//   K4 recur: 16 WGs = 16 batches, 512 thr; Wd in VGPR+LDS
//   K5 loss:  parallel logits/LSE/NLL over the f16 m history

typedef unsigned int uint_t;
typedef unsigned short us_t;
typedef _Float16 h2_t __attribute__((ext_vector_type(2)));

__device__ __forceinline__ us_t f2bf(float f) {
    uint_t u = __float_as_uint(f);
    uint_t r = u + 0x7fffu + ((u >> 16) & 1u);   // RNE
    return (us_t)(r >> 16);
}
__device__ __forceinline__ float bflo(uint_t u) { return __uint_as_float(u << 16); }
__device__ __forceinline__ float bfhi(uint_t u) { return __uint_as_float(u & 0xffff0000u); }

__device__ __forceinline__ us_t f2h(float f) {
    __half h = __float2half(f);                  // RNE
    return *reinterpret_cast<us_t*>(&h);
}
__device__ __forceinline__ float h2f(us_t s) {
    __half h = *reinterpret_cast<__half*>(&s);
    return __half2float(h);
}
__device__ __forceinline__ h2_t u2h2(uint_t u) {
    union { uint_t u; h2_t h; } x; x.u = u; return x.h;
}

#if __has_builtin(__builtin_amdgcn_fdot2)
__device__ __forceinline__ float dot2f(uint_t a, uint_t b, float c) {
    return __builtin_amdgcn_fdot2(u2h2(a), u2h2(b), c, false);
}
#else
__device__ __forceinline__ float dot2f(uint_t a, uint_t b, float c) {
    h2_t x = u2h2(a), y = u2h2(b);
    return c + (float)x.x * (float)y.x + (float)x.y * (float)y.y;
}
#endif

#define DOT4C(q, mc, acc)                                               \
    acc = dot2f(q.x, mc.x, acc);                                        \
    acc = dot2f(q.y, mc.y, acc);                                        \
    acc = dot2f(q.z, mc.z, acc);                                        \
    acc = dot2f(q.w, mc.w, acc);

// ---------------- K1: convert/swizzle weights ----------------
// WdG  [c<64][tid<512][e<8] f16 (uint4 at c*512+tid lane-contiguous):
//      tid -> hg=tid>>6, i=tid&63;  c -> hl=c>>3, jp=c&7
//      h = hg*8 + hl,  j = jp*8 + e
//      val = Wd[h][i*64 + j]   (per-thread register/LDS layout for recur)
// decwY [mm<64][lane<64][k<4] bf16: val = decw[mm*256 + k*64 + lane]
// EWmG [jp<8][h2<128][k<8] f16: val = enc_m_row(j=jp*8+k, h2)
__global__ void cvt_kernel(const float* __restrict__ Wdecw,
                           const float* __restrict__ decw,
                           const float* __restrict__ Wencw,
                           const float* __restrict__ bencw,
                           us_t* __restrict__ WdG, us_t* __restrict__ decwY,
                           us_t* __restrict__ EWmG) {
    int o = blockIdx.x * 256 + threadIdx.x;
    if (o < 262144) {
        int e = o & 7;
        int tq = (o >> 3) & 511;
        int c = o >> 12;
        int hg = tq >> 6, i = tq & 63;
        int hl = c >> 3, jp = c & 7;
        int h = hg * 8 + hl;
        int j = jp * 8 + e;
        WdG[o] = f2h(Wdecw[h * 4096 + i * 64 + j]);
    } else if (o < 278528) {
        int oo = o - 262144;
        int k = oo & 3, lane = (oo >> 2) & 63, mm = oo >> 8;
        decwY[oo] = f2bf(decw[mm * 256 + k * 64 + lane]);
    } else if (o < 286720) {
        int oo = o - 278528;
        int kk = oo & 7, h2 = (oo >> 3) & 127, jp = oo >> 10;
        int j = jp * 8 + kk;
        float v = (h2 < 64) ? Wencw[j * 64 + h2] : bencw[j * 64 + (h2 - 64)];
        EWmG[oo] = f2h(v);
    }
}

// ---------------- K2: token contribution table ----------------
__global__ void build_T(const float* __restrict__ emb, const float* __restrict__ Wencw,
                        const float* __restrict__ bencw, float* __restrict__ T) {
    int l = blockIdx.x >> 8, v = blockIdx.x & 255, h2 = threadIdx.x;  // h2 < 128
    float acc = 0.f;
#pragma unroll
    for (int e = 0; e < 16; ++e) {
        int d = 64 + l * 16 + e;
        float w = (h2 < 64) ? Wencw[d * 64 + h2] : bencw[d * 64 + (h2 - 64)];
        acc += emb[v * 16 + e] * w;
    }
    T[blockIdx.x * 128 + h2] = acc;
}

// ---------------- K3: window precompute P (f32) ----------------
__global__ void build_P(const float* __restrict__ T, const int* __restrict__ x0,
                        const float* __restrict__ Wencb, const float* __restrict__ bencb,
                        float* __restrict__ P) {
    int t = blockIdx.x >> 4, b = blockIdx.x & 15, h2 = threadIdx.x;  // h2 < 128
    float acc = (h2 < 64) ? Wencb[h2] : bencb[h2 - 64];
    for (int l = 0; l < 64; ++l) {
        int p = t + l;
        int v = (p < 64) ? 0 : x0[b * 2048 + (p - 64)];
        acc += T[(l * 256 + v) * 128 + h2];
    }
    P[blockIdx.x * 128 + h2] = acc;
}

// ---------------- K4: sequential recurrence (single WG per batch) ----------
// grid 16: b = blockIdx.x. 512 threads = 8 waves = 2 waves/SIMD (cap 256
// VGPR/wave). thread (hg=tid>>6, i=tid&63) owns h-rows {hg*8+hl : hl<8}:
// hl 0..5 in wreg[48] (192 regs), hl 6..7 in resident LDS (128 KB).
__global__ __launch_bounds__(512, 2) void recur(
    const float* __restrict__ bdecw, const float* __restrict__ bdecb,
    const float* __restrict__ Wdecb, const us_t* __restrict__ WdG,
    const us_t* __restrict__ EWmG, const float* __restrict__ P,
    uint_t* __restrict__ mh32) {
    const int b = blockIdx.x;
    const int tid = threadIdx.x;

    extern __shared__ char smem[];
    uint4*  wlds4   = (uint4*)(smem);              // 131072 [r<2][jp<8][tid<512] uint4
    us_t*   EWm2    = (us_t*)(smem + 131072);      // 16384 [jp][h2][8] f16
    float*  rp_s    = (float*)(smem + 147456);     // 2048 [hg<8][i<64]
    float*  wmp_s   = (float*)(smem + 149504);     // 2048 [hg<8][i<64]
    float*  hbp_s   = (float*)(smem + 151552);     // 2048 [hg<8][i<64]
    float*  hw_s    = (float*)(smem + 153600);     // 256
    uint_t* hb2_s   = (uint_t*)(smem + 153856);    // 128 packed f16 hb pairs
    uint_t* m2_s    = (uint_t*)(smem + 153984);    // 128 packed f16 m pairs
    float*  bias_s  = (float*)(smem + 154112);     // 256
    // total 154368 (dynamic; attribute set at launch). 1 WG/CU.

    const int hg = tid >> 6, iA = tid & 63;

    // ---- init: Wd rows hl 0..5 -> registers, hl 6..7 -> LDS ----
    uint4 wreg[48];
    {
        const uint4* g4 = (const uint4*)WdG;
#pragma unroll
        for (int c = 0; c < 48; ++c) wreg[c] = g4[c * 512 + tid];
        for (int c = 48; c < 64; ++c) wlds4[(c - 48) * 512 + tid] = g4[c * 512 + tid];
    }
    {
        const uint4* g4 = (const uint4*)EWmG;
        uint4* l4 = (uint4*)EWm2;
        for (int k = tid; k < 1024; k += 512) l4[k] = g4[k];
    }
    // Wdb / bdec slices for this thread's (hg, i): jj = hg*4+k, k<4
    uint_t wdbreg[4], bdreg[4];
#pragma unroll
    for (int k = 0; k < 4; ++k) {
        int jj = hg * 4 + k;
        wdbreg[k] = (uint_t)f2h(Wdecb[iA * 64 + 2 * jj])
                  | ((uint_t)f2h(Wdecb[iA * 64 + 2 * jj + 1]) << 16);
        bdreg[k]  = (uint_t)f2h(bdecw[(2 * jj) * 64 + iA])
                  | ((uint_t)f2h(bdecw[(2 * jj + 1) * 64 + iA]) << 16);
    }
    if (tid < 64) bias_s[tid] = bdecb[tid];
    if (tid < 32) m2_s[tid] = 0u;
    __syncthreads();

    float preg = 0.f;
    if (tid < 128) preg = P[b * 128 + tid];  // t = 0

    const uint4* EW4 = (const uint4*)EWm2;
    const uint4* m4 = (const uint4*)m2_s;

    for (int t = 0; t < 2048; ++t) {
        // ---- phase A: P prefetch; V (all waves); henc (waves 0-1) ----
        float pnext = 0.f;
        int tp = (t < 2047) ? (t + 1) : 2047;
        if (tid < 128) pnext = P[(tp * 16 + b) * 128 + tid];

        // V[h][iA] for this thread's 8 h-rows; m chunk per jp is an
        // all-lanes-same-address LDS broadcast. Chain per (h,i): jp
        // ascending, j ascending (same as R13/R15).
        float va[8];
#pragma unroll
        for (int hl = 0; hl < 8; ++hl) va[hl] = 0.f;
#pragma unroll
        for (int jp = 0; jp < 8; ++jp) {
            uint4 mc = m4[jp];
            uint4 q6 = wlds4[(0 * 8 + jp) * 512 + tid];
            uint4 q7 = wlds4[(1 * 8 + jp) * 512 + tid];
#pragma unroll
            for (int hl = 0; hl < 6; ++hl) {
                uint4 q = wreg[hl * 8 + jp];
                DOT4C(q, mc, va[hl]);
            }
            DOT4C(q6, mc, va[6]);
            DOT4C(q7, mc, va[7]);
        }

        if (tid < 128) {
            float acc = preg;
#pragma unroll
            for (int jp = 0; jp < 8; ++jp) {
                uint4 e = EW4[jp * 128 + tid];
                uint4 mc = m4[jp];
                DOT4C(e, mc, acc);
            }
            float sg = 1.f / (1.f + __expf(-acc));
            if (tid < 64) {
                hw_s[tid] = sg;
            } else {
                int l = tid - 64;            // lane within wave 1
                float vlo = __shfl(sg, (l & 31) * 2, 64);
                float vhi = __shfl(sg, (l & 31) * 2 + 1, 64);
                if (l < 32)
                    hb2_s[l] = (uint_t)f2h(vlo) | ((uint_t)f2h(vhi) << 16);
            }
        }
        preg = pnext;
        __syncthreads();   // sync1

        // ---- phase B: hw-weighted partial from OWN va; Wdb*m; bdec*hb ----
        {
            float r0 = 0.f, r1 = 0.f;
#pragma unroll
            for (int hh = 0; hh < 4; ++hh) {
                r0 += hw_s[hg * 8 + 2 * hh]     * va[2 * hh];
                r1 += hw_s[hg * 8 + 2 * hh + 1] * va[2 * hh + 1];
            }
            rp_s[hg * 64 + iA] = r0 + r1;
            float wm = 0.f, hbv = 0.f;
#pragma unroll
            for (int k = 0; k < 4; ++k) {
                wm  = dot2f(wdbreg[k], m2_s[hg * 4 + k], wm);
                hbv = dot2f(bdreg[k],  hb2_s[hg * 4 + k], hbv);
            }
            wmp_s[hg * 64 + iA] = wm;
            hbp_s[hg * 64 + iA] = hbv;
        }
        __syncthreads();   // sync2

        // ---- phase C: assemble m (fixed-order trees) ----
        if (tid < 64) {
            float rs01 = rp_s[tid]       + rp_s[64 + tid];
            float rs23 = rp_s[128 + tid] + rp_s[192 + tid];
            float rs45 = rp_s[256 + tid] + rp_s[320 + tid];
            float rs67 = rp_s[384 + tid] + rp_s[448 + tid];
            float rsum = (rs01 + rs23) + (rs45 + rs67);
            float wm01 = wmp_s[tid]       + wmp_s[64 + tid];
            float wm23 = wmp_s[128 + tid] + wmp_s[192 + tid];
            float wm45 = wmp_s[256 + tid] + wmp_s[320 + tid];
            float wm67 = wmp_s[384 + tid] + wmp_s[448 + tid];
            float wsum = (wm01 + wm23) + (wm45 + wm67);
            float hb01 = hbp_s[tid]       + hbp_s[64 + tid];
            float hb23 = hbp_s[128 + tid] + hbp_s[192 + tid];
            float hb45 = hbp_s[256 + tid] + hbp_s[320 + tid];
            float hb67 = hbp_s[384 + tid] + hbp_s[448 + tid];
            float hsum = (hb01 + hb23) + (hb45 + hb67);
            float r = rsum + wsum + hsum + bias_s[tid];
            float nm = 1.f / (1.f + __expf(-r));
            us_t nh = f2h(nm);                  // f16 round (history dtype)
            uint_t nhu = (uint_t)nh;
            uint_t lo = (uint_t)__shfl((int)nhu, (tid & 31) * 2, 64);
            uint_t hi = (uint_t)__shfl((int)nhu, (tid & 31) * 2 + 1, 64);
            if (tid < 32) {
                uint_t pk = lo | (hi << 16);
                m2_s[tid] = pk;
                mh32[(t * 16 + b) * 32 + tid] = pk;  // history
            }
        }
        __syncthreads();   // sync3
    }
}

// ---------------- K5: parallel loss (reads f16 m history) ----------------
__global__ __launch_bounds__(256) void loss_kernel(
    const us_t* __restrict__ mhb, const us_t* __restrict__ decwY,
    const float* __restrict__ decb, const int* __restrict__ x0,
    float* __restrict__ out) {
    __shared__ __align__(16) us_t dw[16384];   // [mm][lane][k<4] bf16
    const int tid = threadIdx.x;
    {
        const uint4* g4 = (const uint4*)decwY;
        uint4* l4 = (uint4*)dw;
        for (int k = tid; k < 2048; k += 256) l4[k] = g4[k];
    }
    __syncthreads();
    const int lane = tid & 63, wv = tid >> 6;
    const uint2* dwu2 = (const uint2*)dw;
    float b0 = decb[lane], b1 = decb[lane + 64];
    float b2 = decb[lane + 128], b3 = decb[lane + 192];
    for (int r = 0; r < 8; ++r) {
        int row = blockIdx.x * 32 + wv * 8 + r;
        float mL = h2f(mhb[row * 64 + lane]);
        float l0 = b0, l1 = b1, l2 = b2, l3 = b3;
#pragma unroll
        for (int mm = 0; mm < 64; ++mm) {
            float mv = __shfl(mL, mm, 64);
            uint2 q = dwu2[mm * 64 + lane];
            l0 += mv * bflo(q.x);
            l1 += mv * bfhi(q.x);
            l2 += mv * bflo(q.y);
            l3 += mv * bfhi(q.y);
        }
        float mx = fmaxf(fmaxf(l0, l1), fmaxf(l2, l3));
#pragma unroll
        for (int o = 32; o > 0; o >>= 1) mx = fmaxf(mx, __shfl_xor(mx, o, 64));
        float se = __expf(l0 - mx) + __expf(l1 - mx) + __expf(l2 - mx) + __expf(l3 - mx);
#pragma unroll
        for (int o = 32; o > 0; o >>= 1) se += __shfl_xor(se, o, 64);
        float lse = mx + __logf(se);
        int t = row >> 4, bb = row & 15;
        int y = x0[bb * 2048 + t];
        int hi = y >> 6;
        float cand = hi == 0 ? l0 : (hi == 1 ? l1 : (hi == 2 ? l2 : l3));
        float ly = __shfl(cand, y & 63, 64);
        if (lane == 0) out[row] = (lse - ly) * 1.4426950408889634f;
    }
}

extern "C" void kernel_launch(void* const* d_in, const int* in_sizes, int n_in,
                              void* d_out, int out_size, void* d_ws, size_t ws_size,
                              hipStream_t stream) {
    const int*   x0    = (const int*)d_in[0];
    const float* emb   = (const float*)d_in[1];
    const float* Wencw = (const float*)d_in[2];
    const float* Wencb = (const float*)d_in[3];
    const float* Wdecw = (const float*)d_in[4];
    const float* Wdecb = (const float*)d_in[5];
    const float* bencw = (const float*)d_in[6];
    const float* bencb = (const float*)d_in[7];
    const float* bdecw = (const float*)d_in[8];
    const float* bdecb = (const float*)d_in[9];
    const float* decw  = (const float*)d_in[10];
    const float* decb  = (const float*)d_in[11];
    float* out = (float*)d_out;

    char* ws = (char*)d_ws;
    us_t*   WdG   = (us_t*)(ws);                 //       0 .. 524288
    us_t*   decwY = (us_t*)(ws + 524288);        //  524288 .. 557056
    us_t*   EWmG  = (us_t*)(ws + 557056);        //  557056 .. 573440 (16 KB)
    float*  T     = (float*)(ws + 638976);       //  638976 .. 9027584 (8 MB)
    uint_t* mh32  = (uint_t*)T;                  //  alias: T dead after build_P (4 MB)
    float*  P     = (float*)(ws + 9027584);      // 9027584 .. 25804800 (16 MB)

    static const int kRecurLds = 154368;
    (void)hipFuncSetAttribute((const void*)recur,
                              hipFuncAttributeMaxDynamicSharedMemorySize,
                              kRecurLds);

    cvt_kernel<<<1120, 256, 0, stream>>>(Wdecw, decw, Wencw, bencw,
                                         WdG, decwY, EWmG);
    build_T<<<16384, 128, 0, stream>>>(emb, Wencw, bencw, T);
    build_P<<<32768, 128, 0, stream>>>(T, x0, Wencb, bencb, P);
    recur<<<16, 512, kRecurLds, stream>>>(bdecw, bdecb, Wdecb, WdG, EWmG,
                                          P, mh32);
    loss_kernel<<<1024, 256, 0, stream>>>((const us_t*)mh32, decwY, decb, x0, out);
}

// Round 7
// 13113.666 us; speedup vs baseline: 1.0005x; 1.0005x over previous
//
#include <hip/hip_runtime.h>
#include <hip/hip_bf16.h>
#include <hip/hip_fp16.h>

// Hypernetwork RNN scan. B=16, N=2048, M=H=64, L*E=1024, Cout=256.
// Round 20: R19 structure with the LAUNCH-BOUNDS FIX.
// R19 post-mortem: VGPR_Count=128 was not allocator failure — it was the
// __launch_bounds__(512, 2) budget: hipcc's 2nd arg behaves as min BLOCKS
// per CU (R14/R19: (512,2)->128 cap; R15/R16: (256,1)->256 cap). R19's
// true demand (192 Wd regs + ~40 working = ~232) FITS the 256 arch cap.
// Fix: __launch_bounds__(512, 1) -> budget 256, HW runs 2 waves/SIMD x
// 256 regs = the full 512/lane file; 1 WG/CU (LDS-forced anyway).
// Structure (verified-correct in R19, then running off scratch):
//   512 thr/WG, thread (hg=tid>>6, i=tid&63) owns h-rows {hg*8+hl: hl<8}
//   hl 0..5 -> wreg[48] (192 VGPRs); hl 6..7 -> resident LDS (128 KB)
//   Wdb/bdec slices in per-thread regs; products spread over 8 waves.
// Per step: 256 dot2/thread (~1024 cyc/SIMD) + 16 ds_read_b128 + 3 bars,
// ZERO cross-WG traffic, zero global traffic on the serial chain.
//   K1 cvt: Wd->f16 per-thread layout; enc m-rows->f16; dec_w->bf16
//   K2 build_T (f32, 8 MB), K3 build_P (f32, 16 MB)
//   K4 recur: 16 WGs = 16 batches, 512 thr; Wd in VGPR+LDS
//   K5 loss:  parallel logits/LSE/NLL over the f16 m history

typedef unsigned int uint_t;
typedef unsigned short us_t;
typedef _Float16 h2_t __attribute__((ext_vector_type(2)));

__device__ __forceinline__ us_t f2bf(float f) {
    uint_t u = __float_as_uint(f);
    uint_t r = u + 0x7fffu + ((u >> 16) & 1u);   // RNE
    return (us_t)(r >> 16);
}
__device__ __forceinline__ float bflo(uint_t u) { return __uint_as_float(u << 16); }
__device__ __forceinline__ float bfhi(uint_t u) { return __uint_as_float(u & 0xffff0000u); }

__device__ __forceinline__ us_t f2h(float f) {
    __half h = __float2half(f);                  // RNE
    return *reinterpret_cast<us_t*>(&h);
}
__device__ __forceinline__ float h2f(us_t s) {
    __half h = *reinterpret_cast<__half*>(&s);
    return __half2float(h);
}
__device__ __forceinline__ h2_t u2h2(uint_t u) {
    union { uint_t u; h2_t h; } x; x.u = u; return x.h;
}

#if __has_builtin(__builtin_amdgcn_fdot2)
__device__ __forceinline__ float dot2f(uint_t a, uint_t b, float c) {
    return __builtin_amdgcn_fdot2(u2h2(a), u2h2(b), c, false);
}
#else
__device__ __forceinline__ float dot2f(uint_t a, uint_t b, float c) {
    h2_t x = u2h2(a), y = u2h2(b);
    return c + (float)x.x * (float)y.x + (float)x.y * (float)y.y;
}
#endif

#define DOT4C(q, mc, acc)                                               \
    acc = dot2f(q.x, mc.x, acc);                                        \
    acc = dot2f(q.y, mc.y, acc);                                        \
    acc = dot2f(q.z, mc.z, acc);                                        \
    acc = dot2f(q.w, mc.w, acc);

// ---------------- K1: convert/swizzle weights ----------------
// WdG  [c<64][tid<512][e<8] f16 (uint4 at c*512+tid lane-contiguous):
//      tid -> hg=tid>>6, i=tid&63;  c -> hl=c>>3, jp=c&7
//      h = hg*8 + hl,  j = jp*8 + e
//      val = Wd[h][i*64 + j]   (per-thread register/LDS layout for recur)
// decwY [mm<64][lane<64][k<4] bf16: val = decw[mm*256 + k*64 + lane]
// EWmG [jp<8][h2<128][k<8] f16: val = enc_m_row(j=jp*8+k, h2)
__global__ void cvt_kernel(const float* __restrict__ Wdecw,
                           const float* __restrict__ decw,
                           const float* __restrict__ Wencw,
                           const float* __restrict__ bencw,
                           us_t* __restrict__ WdG, us_t* __restrict__ decwY,
                           us_t* __restrict__ EWmG) {
    int o = blockIdx.x * 256 + threadIdx.x;
    if (o < 262144) {
        int e = o & 7;
        int tq = (o >> 3) & 511;
        int c = o >> 12;
        int hg = tq >> 6, i = tq & 63;
        int hl = c >> 3, jp = c & 7;
        int h = hg * 8 + hl;
        int j = jp * 8 + e;
        WdG[o] = f2h(Wdecw[h * 4096 + i * 64 + j]);
    } else if (o < 278528) {
        int oo = o - 262144;
        int k = oo & 3, lane = (oo >> 2) & 63, mm = oo >> 8;
        decwY[oo] = f2bf(decw[mm * 256 + k * 64 + lane]);
    } else if (o < 286720) {
        int oo = o - 278528;
        int kk = oo & 7, h2 = (oo >> 3) & 127, jp = oo >> 10;
        int j = jp * 8 + kk;
        float v = (h2 < 64) ? Wencw[j * 64 + h2] : bencw[j * 64 + (h2 - 64)];
        EWmG[oo] = f2h(v);
    }
}

// ---------------- K2: token contribution table ----------------
__global__ void build_T(const float* __restrict__ emb, const float* __restrict__ Wencw,
                        const float* __restrict__ bencw, float* __restrict__ T) {
    int l = blockIdx.x >> 8, v = blockIdx.x & 255, h2 = threadIdx.x;  // h2 < 128
    float acc = 0.f;
#pragma unroll
    for (int e = 0; e < 16; ++e) {
        int d = 64 + l * 16 + e;
        float w = (h2 < 64) ? Wencw[d * 64 + h2] : bencw[d * 64 + (h2 - 64)];
        acc += emb[v * 16 + e] * w;
    }
    T[blockIdx.x * 128 + h2] = acc;
}

// ---------------- K3: window precompute P (f32) ----------------
__global__ void build_P(const float* __restrict__ T, const int* __restrict__ x0,
                        const float* __restrict__ Wencb, const float* __restrict__ bencb,
                        float* __restrict__ P) {
    int t = blockIdx.x >> 4, b = blockIdx.x & 15, h2 = threadIdx.x;  // h2 < 128
    float acc = (h2 < 64) ? Wencb[h2] : bencb[h2 - 64];
    for (int l = 0; l < 64; ++l) {
        int p = t + l;
        int v = (p < 64) ? 0 : x0[b * 2048 + (p - 64)];
        acc += T[(l * 256 + v) * 128 + h2];
    }
    P[blockIdx.x * 128 + h2] = acc;
}

// ---------------- K4: sequential recurrence (single WG per batch) ----------
// grid 16: b = blockIdx.x. 512 threads = 8 waves = 2 waves/SIMD.
// __launch_bounds__(512, 1): VGPR budget 256/wave (2 x 256 = full file).
__global__ __launch_bounds__(512, 1) void recur(
    const float* __restrict__ bdecw, const float* __restrict__ bdecb,
    const float* __restrict__ Wdecb, const us_t* __restrict__ WdG,
    const us_t* __restrict__ EWmG, const float* __restrict__ P,
    uint_t* __restrict__ mh32) {
    const int b = blockIdx.x;
    const int tid = threadIdx.x;

    extern __shared__ char smem[];
    uint4*  wlds4   = (uint4*)(smem);              // 131072 [r<2][jp<8][tid<512] uint4
    us_t*   EWm2    = (us_t*)(smem + 131072);      // 16384 [jp][h2][8] f16
    float*  rp_s    = (float*)(smem + 147456);     // 2048 [hg<8][i<64]
    float*  wmp_s   = (float*)(smem + 149504);     // 2048 [hg<8][i<64]
    float*  hbp_s   = (float*)(smem + 151552);     // 2048 [hg<8][i<64]
    float*  hw_s    = (float*)(smem + 153600);     // 256
    uint_t* hb2_s   = (uint_t*)(smem + 153856);    // 128 packed f16 hb pairs
    uint_t* m2_s    = (uint_t*)(smem + 153984);    // 128 packed f16 m pairs
    float*  bias_s  = (float*)(smem + 154112);     // 256
    // total 154368 (dynamic; attribute set at launch). 1 WG/CU.

    const int hg = tid >> 6, iA = tid & 63;

    // ---- init: Wd rows hl 0..5 -> registers, hl 6..7 -> LDS ----
    uint4 wreg[48];
    {
        const uint4* g4 = (const uint4*)WdG;
#pragma unroll
        for (int c = 0; c < 48; ++c) wreg[c] = g4[c * 512 + tid];
        for (int c = 48; c < 64; ++c) wlds4[(c - 48) * 512 + tid] = g4[c * 512 + tid];
    }
    {
        const uint4* g4 = (const uint4*)EWmG;
        uint4* l4 = (uint4*)EWm2;
        for (int k = tid; k < 1024; k += 512) l4[k] = g4[k];
    }
    // Wdb / bdec slices for this thread's (hg, i): jj = hg*4+k, k<4
    uint_t wdbreg[4], bdreg[4];
#pragma unroll
    for (int k = 0; k < 4; ++k) {
        int jj = hg * 4 + k;
        wdbreg[k] = (uint_t)f2h(Wdecb[iA * 64 + 2 * jj])
                  | ((uint_t)f2h(Wdecb[iA * 64 + 2 * jj + 1]) << 16);
        bdreg[k]  = (uint_t)f2h(bdecw[(2 * jj) * 64 + iA])
                  | ((uint_t)f2h(bdecw[(2 * jj + 1) * 64 + iA]) << 16);
    }
    if (tid < 64) bias_s[tid] = bdecb[tid];
    if (tid < 32) m2_s[tid] = 0u;
    __syncthreads();

    float preg = 0.f;
    if (tid < 128) preg = P[b * 128 + tid];  // t = 0

    const uint4* EW4 = (const uint4*)EWm2;
    const uint4* m4 = (const uint4*)m2_s;

    for (int t = 0; t < 2048; ++t) {
        // ---- phase A: P prefetch; V (all waves); henc (waves 0-1) ----
        float pnext = 0.f;
        int tp = (t < 2047) ? (t + 1) : 2047;
        if (tid < 128) pnext = P[(tp * 16 + b) * 128 + tid];

        // V[h][iA] for this thread's 8 h-rows; m chunk per jp is an
        // all-lanes-same-address LDS broadcast. Chain per (h,i): jp
        // ascending, j ascending (same as R13/R19).
        float va[8];
#pragma unroll
        for (int hl = 0; hl < 8; ++hl) va[hl] = 0.f;
#pragma unroll
        for (int jp = 0; jp < 8; ++jp) {
            uint4 mc = m4[jp];
            uint4 q6 = wlds4[(0 * 8 + jp) * 512 + tid];
            uint4 q7 = wlds4[(1 * 8 + jp) * 512 + tid];
#pragma unroll
            for (int hl = 0; hl < 6; ++hl) {
                uint4 q = wreg[hl * 8 + jp];
                DOT4C(q, mc, va[hl]);
            }
            DOT4C(q6, mc, va[6]);
            DOT4C(q7, mc, va[7]);
        }

        if (tid < 128) {
            float acc = preg;
#pragma unroll
            for (int jp = 0; jp < 8; ++jp) {
                uint4 e = EW4[jp * 128 + tid];
                uint4 mc = m4[jp];
                DOT4C(e, mc, acc);
            }
            float sg = 1.f / (1.f + __expf(-acc));
            if (tid < 64) {
                hw_s[tid] = sg;
            } else {
                int l = tid - 64;            // lane within wave 1
                float vlo = __shfl(sg, (l & 31) * 2, 64);
                float vhi = __shfl(sg, (l & 31) * 2 + 1, 64);
                if (l < 32)
                    hb2_s[l] = (uint_t)f2h(vlo) | ((uint_t)f2h(vhi) << 16);
            }
        }
        preg = pnext;
        __syncthreads();   // sync1

        // ---- phase B: hw-weighted partial from OWN va; Wdb*m; bdec*hb ----
        {
            float r0 = 0.f, r1 = 0.f;
#pragma unroll
            for (int hh = 0; hh < 4; ++hh) {
                r0 += hw_s[hg * 8 + 2 * hh]     * va[2 * hh];
                r1 += hw_s[hg * 8 + 2 * hh + 1] * va[2 * hh + 1];
            }
            rp_s[hg * 64 + iA] = r0 + r1;
            float wm = 0.f, hbv = 0.f;
#pragma unroll
            for (int k = 0; k < 4; ++k) {
                wm  = dot2f(wdbreg[k], m2_s[hg * 4 + k], wm);
                hbv = dot2f(bdreg[k],  hb2_s[hg * 4 + k], hbv);
            }
            wmp_s[hg * 64 + iA] = wm;
            hbp_s[hg * 64 + iA] = hbv;
        }
        __syncthreads();   // sync2

        // ---- phase C: assemble m (fixed-order trees) ----
        if (tid < 64) {
            float rs01 = rp_s[tid]       + rp_s[64 + tid];
            float rs23 = rp_s[128 + tid] + rp_s[192 + tid];
            float rs45 = rp_s[256 + tid] + rp_s[320 + tid];
            float rs67 = rp_s[384 + tid] + rp_s[448 + tid];
            float rsum = (rs01 + rs23) + (rs45 + rs67);
            float wm01 = wmp_s[tid]       + wmp_s[64 + tid];
            float wm23 = wmp_s[128 + tid] + wmp_s[192 + tid];
            float wm45 = wmp_s[256 + tid] + wmp_s[320 + tid];
            float wm67 = wmp_s[384 + tid] + wmp_s[448 + tid];
            float wsum = (wm01 + wm23) + (wm45 + wm67);
            float hb01 = hbp_s[tid]       + hbp_s[64 + tid];
            float hb23 = hbp_s[128 + tid] + hbp_s[192 + tid];
            float hb45 = hbp_s[256 + tid] + hbp_s[320 + tid];
            float hb67 = hbp_s[384 + tid] + hbp_s[448 + tid];
            float hsum = (hb01 + hb23) + (hb45 + hb67);
            float r = rsum + wsum + hsum + bias_s[tid];
            float nm = 1.f / (1.f + __expf(-r));
            us_t nh = f2h(nm);                  // f16 round (history dtype)
            uint_t nhu = (uint_t)nh;
            uint_t lo = (uint_t)__shfl((int)nhu, (tid & 31) * 2, 64);
            uint_t hi = (uint_t)__shfl((int)nhu, (tid & 31) * 2 + 1, 64);
            if (tid < 32) {
                uint_t pk = lo | (hi << 16);
                m2_s[tid] = pk;
                mh32[(t * 16 + b) * 32 + tid] = pk;  // history
            }
        }
        __syncthreads();   // sync3
    }
}

// ---------------- K5: parallel loss (reads f16 m history) ----------------
__global__ __launch_bounds__(256) void loss_kernel(
    const us_t* __restrict__ mhb, const us_t* __restrict__ decwY,
    const float* __restrict__ decb, const int* __restrict__ x0,
    float* __restrict__ out) {
    __shared__ __align__(16) us_t dw[16384];   // [mm][lane][k<4] bf16
    const int tid = threadIdx.x;
    {
        const uint4* g4 = (const uint4*)decwY;
        uint4* l4 = (uint4*)dw;
        for (int k = tid; k < 2048; k += 256) l4[k] = g4[k];
    }
    __syncthreads();
    const int lane = tid & 63, wv = tid >> 6;
    const uint2* dwu2 = (const uint2*)dw;
    float b0 = decb[lane], b1 = decb[lane + 64];
    float b2 = decb[lane + 128], b3 = decb[lane + 192];
    for (int r = 0; r < 8; ++r) {
        int row = blockIdx.x * 32 + wv * 8 + r;
        float mL = h2f(mhb[row * 64 + lane]);
        float l0 = b0, l1 = b1, l2 = b2, l3 = b3;
#pragma unroll
        for (int mm = 0; mm < 64; ++mm) {
            float mv = __shfl(mL, mm, 64);
            uint2 q = dwu2[mm * 64 + lane];
            l0 += mv * bflo(q.x);
            l1 += mv * bfhi(q.x);
            l2 += mv * bflo(q.y);
            l3 += mv * bfhi(q.y);
        }
        float mx = fmaxf(fmaxf(l0, l1), fmaxf(l2, l3));
#pragma unroll
        for (int o = 32; o > 0; o >>= 1) mx = fmaxf(mx, __shfl_xor(mx, o, 64));
        float se = __expf(l0 - mx) + __expf(l1 - mx) + __expf(l2 - mx) + __expf(l3 - mx);
#pragma unroll
        for (int o = 32; o > 0; o >>= 1) se += __shfl_xor(se, o, 64);
        float lse = mx + __logf(se);
        int t = row >> 4, bb = row & 15;
        int y = x0[bb * 2048 + t];
        int hi = y >> 6;
        float cand = hi == 0 ? l0 : (hi == 1 ? l1 : (hi == 2 ? l2 : l3));
        float ly = __shfl(cand, y & 63, 64);
        if (lane == 0) out[row] = (lse - ly) * 1.4426950408889634f;
    }
}

extern "C" void kernel_launch(void* const* d_in, const int* in_sizes, int n_in,
                              void* d_out, int out_size, void* d_ws, size_t ws_size,
                              hipStream_t stream) {
    const int*   x0    = (const int*)d_in[0];
    const float* emb   = (const float*)d_in[1];
    const float* Wencw = (const float*)d_in[2];
    const float* Wencb = (const float*)d_in[3];
    const float* Wdecw = (const float*)d_in[4];
    const float* Wdecb = (const float*)d_in[5];
    const float* bencw = (const float*)d_in[6];
    const float* bencb = (const float*)d_in[7];
    const float* bdecw = (const float*)d_in[8];
    const float* bdecb = (const float*)d_in[9];
    const float* decw  = (const float*)d_in[10];
    const float* decb  = (const float*)d_in[11];
    float* out = (float*)d_out;

    char* ws = (char*)d_ws;
    us_t*   WdG   = (us_t*)(ws);                 //       0 .. 524288
    us_t*   decwY = (us_t*)(ws + 524288);        //  524288 .. 557056
    us_t*   EWmG  = (us_t*)(ws + 557056);        //  557056 .. 573440 (16 KB)
    float*  T     = (float*)(ws + 638976);       //  638976 .. 9027584 (8 MB)
    uint_t* mh32  = (uint_t*)T;                  //  alias: T dead after build_P (4 MB)
    float*  P     = (float*)(ws + 9027584);      // 9027584 .. 25804800 (16 MB)

    static const int kRecurLds = 154368;
    (void)hipFuncSetAttribute((const void*)recur,
                              hipFuncAttributeMaxDynamicSharedMemorySize,
                              kRecurLds);

    cvt_kernel<<<1120, 256, 0, stream>>>(Wdecw, decw, Wencw, bencw,
                                         WdG, decwY, EWmG);
    build_T<<<16384, 128, 0, stream>>>(emb, Wencw, bencw, T);
    build_P<<<32768, 128, 0, stream>>>(T, x0, Wencb, bencb, P);
    recur<<<16, 512, kRecurLds, stream>>>(bdecw, bdecb, Wdecb, WdG, EWmG,
                                          P, mh32);
    loss_kernel<<<1024, 256, 0, stream>>>((const us_t*)mh32, decwY, decb, x0, out);
}

// Round 8
// 4018.182 us; speedup vs baseline: 3.2652x; 3.2636x over previous
//
#include <hip/hip_runtime.h>
#include <hip/hip_bf16.h>
#include <hip/hip_fp16.h>

// Hypernetwork RNN scan. B=16, N=2048, M=H=64, L*E=1024, Cout=256.
// Round 21: R13 (best verified, 3276 us) + PIPELINED POLLING.
// R14-R20 post-mortem closed the single-WG branch: a CU's registers
// (<=256 KB addressable; 512-thr WGs cap at 128 VGPR, 256-thr at 256)
// plus LDS cannot hold Wd (512 KB). The 4-WG h-slice exchange stands.
// R13's measured exchange stall (~1900 cyc) decomposes as poll
// QUANTIZATION, not raw RTT: serial {load; vmcnt(0); ballot; s_sleep}
// has ~700-cyc probe period and each probe samples state at issue time
// -> detect ~= 2 periods + latency ~= 1900. Fix: 4 outstanding relaxed
// atomic loads, rotating checks (compiler emits vmcnt(3) partial waits)
// -> probe spacing ~latency/4 -> detect ~= visible + latency + 150
// ~= 1400 cyc. No numerical change anywhere (same payloads/order).
//   K1 cvt: Wd->f16 h-slice layout; enc m-rows->f16; dec_w->bf16 (loss)
//   K2 build_T (f32, 8 MB), K3 build_P (f32, 16 MB)
//   K4 recur: 64 WGs = 16 batches x 4 h-slices; Wd in VGPRs
//   K5 loss:  parallel logits/LSE/NLL over the f16 m history

typedef unsigned int uint_t;
typedef unsigned short us_t;
typedef unsigned long long u64_t;
typedef _Float16 h2_t __attribute__((ext_vector_type(2)));

__device__ __forceinline__ us_t f2bf(float f) {
    uint_t u = __float_as_uint(f);
    uint_t r = u + 0x7fffu + ((u >> 16) & 1u);   // RNE
    return (us_t)(r >> 16);
}
__device__ __forceinline__ float bflo(uint_t u) { return __uint_as_float(u << 16); }
__device__ __forceinline__ float bfhi(uint_t u) { return __uint_as_float(u & 0xffff0000u); }

__device__ __forceinline__ us_t f2h(float f) {
    __half h = __float2half(f);                  // RNE
    return *reinterpret_cast<us_t*>(&h);
}
__device__ __forceinline__ float h2f(us_t s) {
    __half h = *reinterpret_cast<__half*>(&s);
    return __half2float(h);
}
__device__ __forceinline__ h2_t u2h2(uint_t u) {
    union { uint_t u; h2_t h; } x; x.u = u; return x.h;
}

#if __has_builtin(__builtin_amdgcn_fdot2)
__device__ __forceinline__ float dot2f(uint_t a, uint_t b, float c) {
    return __builtin_amdgcn_fdot2(u2h2(a), u2h2(b), c, false);
}
#else
__device__ __forceinline__ float dot2f(uint_t a, uint_t b, float c) {
    h2_t x = u2h2(a), y = u2h2(b);
    return c + (float)x.x * (float)y.x + (float)x.y * (float)y.y;
}
#endif

#define DOT4(q, base, acc)                                              \
    acc = dot2f(q.x, mreg2u[(base) + 0], acc);                          \
    acc = dot2f(q.y, mreg2u[(base) + 1], acc);                          \
    acc = dot2f(q.z, mreg2u[(base) + 2], acc);                          \
    acc = dot2f(q.w, mreg2u[(base) + 3], acc);

// ---------------- K1: convert/swizzle weights ----------------
// WdG  [s<4][jp<8][o<1024][k<8] f16: h = s*16 + (o>>6), i = o&63, j = jp*8+k
//      val = Wd[h][i*64 + j]   (h-slice layout; uint4 at jp*1024+o lane-contig)
// decwY [mm<64][lane<64][k<4] bf16: val = decw[mm*256 + k*64 + lane]
// EWmG [jp<8][h2<128][k<8] f16: val = enc_m_row(j=jp*8+k, h2)
__global__ void cvt_kernel(const float* __restrict__ Wdecw,
                           const float* __restrict__ decw,
                           const float* __restrict__ Wencw,
                           const float* __restrict__ bencw,
                           us_t* __restrict__ WdG, us_t* __restrict__ decwY,
                           us_t* __restrict__ EWmG) {
    int o = blockIdx.x * 256 + threadIdx.x;
    if (o < 262144) {
        int s = o >> 16;
        int idx = o & 65535;
        int k = idx & 7;
        int oo = (idx >> 3) & 1023;
        int jp = idx >> 13;
        int h = s * 16 + (oo >> 6);
        int i = oo & 63;
        int j = jp * 8 + k;
        WdG[o] = f2h(Wdecw[h * 4096 + i * 64 + j]);
    } else if (o < 278528) {
        int oo = o - 262144;
        int k = oo & 3, lane = (oo >> 2) & 63, mm = oo >> 8;
        decwY[oo] = f2bf(decw[mm * 256 + k * 64 + lane]);
    } else if (o < 286720) {
        int oo = o - 278528;
        int kk = oo & 7, h2 = (oo >> 3) & 127, jp = oo >> 10;
        int j = jp * 8 + kk;
        float v = (h2 < 64) ? Wencw[j * 64 + h2] : bencw[j * 64 + (h2 - 64)];
        EWmG[oo] = f2h(v);
    }
}

// ---------------- K2: token contribution table ----------------
__global__ void build_T(const float* __restrict__ emb, const float* __restrict__ Wencw,
                        const float* __restrict__ bencw, float* __restrict__ T) {
    int l = blockIdx.x >> 8, v = blockIdx.x & 255, h2 = threadIdx.x;  // h2 < 128
    float acc = 0.f;
#pragma unroll
    for (int e = 0; e < 16; ++e) {
        int d = 64 + l * 16 + e;
        float w = (h2 < 64) ? Wencw[d * 64 + h2] : bencw[d * 64 + (h2 - 64)];
        acc += emb[v * 16 + e] * w;
    }
    T[blockIdx.x * 128 + h2] = acc;
}

// ---------------- K3: window precompute P (f32) ----------------
__global__ void build_P(const float* __restrict__ T, const int* __restrict__ x0,
                        const float* __restrict__ Wencb, const float* __restrict__ bencb,
                        float* __restrict__ P) {
    int t = blockIdx.x >> 4, b = blockIdx.x & 15, h2 = threadIdx.x;  // h2 < 128
    float acc = (h2 < 64) ? Wencb[h2] : bencb[h2 - 64];
    for (int l = 0; l < 64; ++l) {
        int p = t + l;
        int v = (p < 64) ? 0 : x0[b * 2048 + (p - 64)];
        acc += T[(l * 256 + v) * 128 + h2];
    }
    P[blockIdx.x * 128 + h2] = acc;
}

// ---------------- K4: sequential recurrence (h-slice) ----------------
// grid 64: b = blk&15, s = blk>>4. ~40 KB live LDS + pad to 157632 -> 1 WG/CU.
__global__ __launch_bounds__(512, 2) void recur(
    const float* __restrict__ bdecw, const float* __restrict__ bdecb,
    const float* __restrict__ Wdecb, const us_t* __restrict__ WdG,
    const us_t* __restrict__ EWmG, const float* __restrict__ P,
    uint_t* __restrict__ mh32, u64_t* __restrict__ pxb) {
    const int b = blockIdx.x & 15, s = blockIdx.x >> 4;
    const int tid = threadIdx.x;

    extern __shared__ char smem[];
    us_t*   EWm2   = (us_t*)(smem);                // 16384 [jp][h2][8] f16
    uint_t* wdbt2  = (uint_t*)(smem + 16384);      // 8192 [jj<32][i<64]: (Wdb[i][2jj],Wdb[i][2jj+1]) f16
    uint_t* bdec2  = (uint_t*)(smem + 24576);      // 8192 [hh<32][i<64]: (bdec[2hh][i],bdec[2hh+1][i]) f16
    float*  V_s    = (float*)(smem + 32768);       // 4160 [hl<16][i<64] stride 65
    float*  rp4_s  = (float*)(smem + 36928);       // 1024 [p<4][i]
    float*  wdbm2_s= (float*)(smem + 37952);       // 512  [q<2][i]
    float*  hbb2_s = (float*)(smem + 38464);       // 512  [q<2][i]
    float*  hw_s   = (float*)(smem + 38976);       // 256
    uint_t* hb2_s  = (uint_t*)(smem + 39232);      // 128 packed f16 hb pairs
    uint_t* m2_s   = (uint_t*)(smem + 39360);      // 128 packed f16 m pairs
    float*  bias_s = (float*)(smem + 39488);       // 256
    // live total 39744; pad to 157632 at launch (1 WG/CU)

    // ---- init: Wd h-slice -> registers (rows o=tid, o=tid+512) ----
    uint4 wreg[16];
    {
        const uint4* g4 = (const uint4*)WdG + s * 8192;
#pragma unroll
        for (int jp = 0; jp < 8; ++jp) {
            wreg[jp]     = g4[jp * 1024 + tid];
            wreg[8 + jp] = g4[jp * 1024 + tid + 512];
        }
    }
    {
        const uint4* g4 = (const uint4*)EWmG;
        uint4* l4 = (uint4*)EWm2;
        for (int k = tid; k < 1024; k += 512) l4[k] = g4[k];
    }
    for (int k = tid; k < 2048; k += 512) {
        int jj = k >> 6, i = k & 63;
        wdbt2[k] = (uint_t)f2h(Wdecb[i * 64 + 2 * jj])
                 | ((uint_t)f2h(Wdecb[i * 64 + 2 * jj + 1]) << 16);
        bdec2[k] = (uint_t)f2h(bdecw[(2 * jj) * 64 + i])
                 | ((uint_t)f2h(bdecw[(2 * jj + 1) * 64 + i]) << 16);
    }
    if (tid < 64) bias_s[tid] = bdecb[tid];
    if (tid < 32) m2_s[tid] = 0u;
    __syncthreads();

    // persistent m as 32 packed half2 regs; COMPILE-TIME indexing only
    // (Round-3 lesson: any runtime index demotes the array to scratch).
    uint_t mreg2u[32];
#pragma unroll
    for (int j = 0; j < 32; ++j) mreg2u[j] = 0u;

    float preg = 0.f;
    if (tid < 128) preg = P[b * 128 + tid];  // t = 0

    const uint4* EW4 = (const uint4*)EWm2;
    const int hl = tid >> 6, iA = tid & 63;
    const int w = tid >> 6;   // wave index

    for (int t = 0; t < 2048; ++t) {
        // ---- phase A: P prefetch; V slice (Wd regs); henc; hb pack ----
        float pnext = 0.f;
        int tp = (t < 2047) ? (t + 1) : 2047;
        if (tid < 128) pnext = P[(tp * 16 + b) * 128 + tid];

        float a0 = 0.f, a1 = 0.f;
#pragma unroll
        for (int jp = 0; jp < 8; ++jp) {
            uint4 q0 = wreg[jp];
            uint4 q1 = wreg[8 + jp];
            DOT4(q0, jp * 4, a0);
            DOT4(q1, jp * 4, a1);
        }
        V_s[hl * 65 + iA] = a0;        // h_local = hl
        V_s[(hl + 8) * 65 + iA] = a1;  // h_local = hl + 8

        if (tid < 128) {
            float acc = preg;
#pragma unroll
            for (int jp = 0; jp < 8; ++jp) {
                uint4 e = EW4[jp * 128 + tid];
                DOT4(e, jp * 4, acc);
            }
            float sg = 1.f / (1.f + __expf(-acc));
            if (tid < 64) {
                hw_s[tid] = sg;
            } else {
                int l = tid - 64;            // lane within wave 1
                float vlo = __shfl(sg, (l & 31) * 2, 64);
                float vhi = __shfl(sg, (l & 31) * 2 + 1, 64);
                if (l < 32)
                    hb2_s[l] = (uint_t)f2h(vlo) | ((uint_t)f2h(vhi) << 16);
            }
        }
        preg = pnext;
        __syncthreads();   // sync1

        // ---- exchange phase ----
        u64_t* slotb = pxb + (u64_t)(((t & 1) * 16 + b) * 4) * 64;
        const uint_t tg = (uint_t)(t + 1);

        if (tid < 64) {
            // wave 0: own partial r_s[i] over the 16 owned h, then publish
            float r0 = 0.f, r1 = 0.f;
#pragma unroll
            for (int hh = 0; hh < 8; ++hh) {
                r0 += hw_s[s * 16 + 2 * hh]     * V_s[(2 * hh) * 65 + tid];
                r1 += hw_s[s * 16 + 2 * hh + 1] * V_s[(2 * hh + 1) * 65 + tid];
            }
            float rs = r0 + r1;
            rp4_s[s * 64 + tid] = rs;
            u64_t pay = ((u64_t)tg << 32) | (u64_t)__float_as_uint(rs);
            __hip_atomic_store(slotb + s * 64 + tid, pay,
                               __ATOMIC_RELAXED, __HIP_MEMORY_SCOPE_AGENT);
        }

        if (w < 3) {
            // polling waves 0,1,2: one peer slot each; detection IS payload.
            // 4 outstanding relaxed loads, rotating checks: probe spacing
            // ~latency/4 instead of a full serial-load period (R21 change).
            int p = w + (w >= s ? 1 : 0);
            int lane = tid & 63;
            const u64_t* src = slotb + p * 64 + lane;
#define PLOAD() __hip_atomic_load(src, __ATOMIC_RELAXED, __HIP_MEMORY_SCOPE_AGENT)
            u64_t v0 = PLOAD();
            u64_t v1 = PLOAD();
            u64_t v2 = PLOAD();
            u64_t v3 = PLOAD();
            u64_t v;
            for (;;) {
                if (__ballot((uint_t)(v0 >> 32) == tg) == ~0ull) { v = v0; break; }
                v0 = PLOAD();
                if (__ballot((uint_t)(v1 >> 32) == tg) == ~0ull) { v = v1; break; }
                v1 = PLOAD();
                if (__ballot((uint_t)(v2 >> 32) == tg) == ~0ull) { v = v2; break; }
                v2 = PLOAD();
                if (__ballot((uint_t)(v3 >> 32) == tg) == ~0ull) { v = v3; break; }
                v3 = PLOAD();
            }
#undef PLOAD
            rp4_s[p * 64 + lane] = __uint_as_float((uint_t)v);
        } else if (w < 5) {
            // worker waves 3,4: local terms, overlapped with the RTT
            int i = tid & 63;
            float wm = 0.f, hbv = 0.f;
            if (w == 3) {
#pragma unroll
                for (int jj = 0; jj < 16; ++jj) {
                    wm  = dot2f(wdbt2[jj * 64 + i], mreg2u[jj], wm);
                    hbv = dot2f(bdec2[jj * 64 + i], hb2_s[jj], hbv);
                }
                wdbm2_s[i] = wm;
                hbb2_s[i] = hbv;
            } else {
#pragma unroll
                for (int jj = 0; jj < 16; ++jj) {
                    wm  = dot2f(wdbt2[(16 + jj) * 64 + i], mreg2u[16 + jj], wm);
                    hbv = dot2f(bdec2[(16 + jj) * 64 + i], hb2_s[16 + jj], hbv);
                }
                wdbm2_s[64 + i] = wm;
                hbb2_s[64 + i] = hbv;
            }
        }
        __syncthreads();   // sync2

        // ---- final: assemble identical full m locally (fixed order) ----
        if (tid < 64) {
            float r = ((rp4_s[tid] + rp4_s[64 + tid])
                     + (rp4_s[128 + tid] + rp4_s[192 + tid]))
                    + (wdbm2_s[tid] + wdbm2_s[64 + tid])
                    + (hbb2_s[tid] + hbb2_s[64 + tid])
                    + bias_s[tid];
            float nm = 1.f / (1.f + __expf(-r));
            us_t nh = f2h(nm);                  // f16 round: all WGs agree
            uint_t nhu = (uint_t)nh;
            uint_t lo = (uint_t)__shfl((int)nhu, (tid & 31) * 2, 64);
            uint_t hi = (uint_t)__shfl((int)nhu, (tid & 31) * 2 + 1, 64);
            if (tid < 32) {
                uint_t pk = lo | (hi << 16);
                m2_s[tid] = pk;
                if (s == 0) mh32[(t * 16 + b) * 32 + tid] = pk;  // history
            }
        }
        __syncthreads();   // sync3

        // ---- reload packed m into persistent registers ----
        {
            const uint4* mg = (const uint4*)m2_s;
#pragma unroll
            for (int p = 0; p < 8; ++p) {
                uint4 v = mg[p];
                mreg2u[p * 4 + 0] = v.x;
                mreg2u[p * 4 + 1] = v.y;
                mreg2u[p * 4 + 2] = v.z;
                mreg2u[p * 4 + 3] = v.w;
            }
        }
    }
}

// ---------------- K5: parallel loss (reads f16 m history) ----------------
__global__ __launch_bounds__(256) void loss_kernel(
    const us_t* __restrict__ mhb, const us_t* __restrict__ decwY,
    const float* __restrict__ decb, const int* __restrict__ x0,
    float* __restrict__ out) {
    __shared__ __align__(16) us_t dw[16384];   // [mm][lane][k<4] bf16
    const int tid = threadIdx.x;
    {
        const uint4* g4 = (const uint4*)decwY;
        uint4* l4 = (uint4*)dw;
        for (int k = tid; k < 2048; k += 256) l4[k] = g4[k];
    }
    __syncthreads();
    const int lane = tid & 63, wv = tid >> 6;
    const uint2* dwu2 = (const uint2*)dw;
    float b0 = decb[lane], b1 = decb[lane + 64];
    float b2 = decb[lane + 128], b3 = decb[lane + 192];
    for (int r = 0; r < 8; ++r) {
        int row = blockIdx.x * 32 + wv * 8 + r;
        float mL = h2f(mhb[row * 64 + lane]);
        float l0 = b0, l1 = b1, l2 = b2, l3 = b3;
#pragma unroll
        for (int mm = 0; mm < 64; ++mm) {
            float mv = __shfl(mL, mm, 64);
            uint2 q = dwu2[mm * 64 + lane];
            l0 += mv * bflo(q.x);
            l1 += mv * bfhi(q.x);
            l2 += mv * bflo(q.y);
            l3 += mv * bfhi(q.y);
        }
        float mx = fmaxf(fmaxf(l0, l1), fmaxf(l2, l3));
#pragma unroll
        for (int o = 32; o > 0; o >>= 1) mx = fmaxf(mx, __shfl_xor(mx, o, 64));
        float se = __expf(l0 - mx) + __expf(l1 - mx) + __expf(l2 - mx) + __expf(l3 - mx);
#pragma unroll
        for (int o = 32; o > 0; o >>= 1) se += __shfl_xor(se, o, 64);
        float lse = mx + __logf(se);
        int t = row >> 4, bb = row & 15;
        int y = x0[bb * 2048 + t];
        int hi = y >> 6;
        float cand = hi == 0 ? l0 : (hi == 1 ? l1 : (hi == 2 ? l2 : l3));
        float ly = __shfl(cand, y & 63, 64);
        if (lane == 0) out[row] = (lse - ly) * 1.4426950408889634f;
    }
}

extern "C" void kernel_launch(void* const* d_in, const int* in_sizes, int n_in,
                              void* d_out, int out_size, void* d_ws, size_t ws_size,
                              hipStream_t stream) {
    const int*   x0    = (const int*)d_in[0];
    const float* emb   = (const float*)d_in[1];
    const float* Wencw = (const float*)d_in[2];
    const float* Wencb = (const float*)d_in[3];
    const float* Wdecw = (const float*)d_in[4];
    const float* Wdecb = (const float*)d_in[5];
    const float* bencw = (const float*)d_in[6];
    const float* bencb = (const float*)d_in[7];
    const float* bdecw = (const float*)d_in[8];
    const float* bdecb = (const float*)d_in[9];
    const float* decw  = (const float*)d_in[10];
    const float* decb  = (const float*)d_in[11];
    float* out = (float*)d_out;

    char* ws = (char*)d_ws;
    us_t*   WdG   = (us_t*)(ws);                 //       0 .. 524288
    us_t*   decwY = (us_t*)(ws + 524288);        //  524288 .. 557056
    us_t*   EWmG  = (us_t*)(ws + 557056);        //  557056 .. 573440 (16 KB)
    u64_t*  pxb   = (u64_t*)(ws + 573440);       //  573440 .. 638976 (64 KB, 2-parity)
    float*  T     = (float*)(ws + 638976);       //  638976 .. 9027584 (8 MB)
    uint_t* mh32  = (uint_t*)T;                  //  alias: T dead after build_P (4 MB)
    float*  P     = (float*)(ws + 9027584);      // 9027584 .. 25804800 (16 MB)

    static const int kRecurLds = 157632;
    (void)hipFuncSetAttribute((const void*)recur,
                              hipFuncAttributeMaxDynamicSharedMemorySize,
                              kRecurLds);

    cvt_kernel<<<1120, 256, 0, stream>>>(Wdecw, decw, Wencw, bencw,
                                         WdG, decwY, EWmG);
    build_T<<<16384, 128, 0, stream>>>(emb, Wencw, bencw, T);
    build_P<<<32768, 128, 0, stream>>>(T, x0, Wencb, bencb, P);
    // zero the tag mailbox (tag 0 never matches t+1 >= 1)
    (void)hipMemsetAsync(pxb, 0, 65536, stream);
    recur<<<64, 512, kRecurLds, stream>>>(bdecw, bdecb, Wdecb, WdG, EWmG,
                                          P, mh32, pxb);
    loss_kernel<<<1024, 256, 0, stream>>>((const us_t*)mh32, decwY, decb, x0, out);
}